// Round 7
// baseline (786.137 us; speedup 1.0000x reference)
//
#include <hip/hip_runtime.h>

#define TT 512

typedef _Float16 h2_t  __attribute__((ext_vector_type(2)));
typedef _Float16 f16x4 __attribute__((ext_vector_type(4)));
typedef float    f32x4 __attribute__((ext_vector_type(4)));
typedef float    f32x4u __attribute__((ext_vector_type(4), aligned(4)));
typedef unsigned int u32x2_t __attribute__((ext_vector_type(2)));

__device__ __forceinline__ float frcp(float x){ return __builtin_amdgcn_rcpf(x); }
__device__ __forceinline__ float frsq(float x){ return __builtin_amdgcn_rsqf(x); }
__device__ __forceinline__ float sigm(float x){ return frcp(1.0f + __expf(-x)); }
__device__ __forceinline__ float tanh_fast(float x){
    x = fminf(15.0f, fmaxf(-15.0f, x));
    float e = __expf(2.0f * x);
    return (e - 1.0f) * frcp(e + 1.0f);
}
__device__ __forceinline__ float fdot2(h2_t a, h2_t b, float c){
    return __builtin_amdgcn_fdot2(a, b, c, false);
}
__device__ __forceinline__ h2_t pk16(float a, float b){
    return __builtin_bit_cast(h2_t, __builtin_amdgcn_cvt_pkrtz(a, b));
}
__device__ __forceinline__ f16x4 mk4(float a, float b, float c, float d){
    u32x2_t u;
    u[0] = __builtin_bit_cast(unsigned int, pk16(a, b));
    u[1] = __builtin_bit_cast(unsigned int, pk16(c, d));
    return __builtin_bit_cast(f16x4, u);
}
__device__ __forceinline__ f32x4 mfma16(f16x4 a, f16x4 b, f32x4 c){
    return __builtin_amdgcn_mfma_f32_16x16x16f16(a, b, c, 0, 0, 0);
}

// 2-REGION SOFTWARE PIPELINE (rounds 3/4 structure) + V2-VERBATIM K-exchange.
// Bisection rounds 2-6 isolated the 264.5-absmax bug to the stride-20 s_K
// layout (round 5: flat loop + that layout FAILED with the identical error
// as the pipelined rounds 3/4; round 6: flat loop + V2 layout PASSED).
// The pipeline itself added zero error delta -> reinstated here, with the
// verified s_Kp[24][16] exchange, V2 masked wih loads, __syncthreads.
//
// 4 waves/block, 16 batch elems/block, M-split: wave w owns h rows
// 16w..16w+15 (gate tiles {w,4+w,8+w}); 1024 waves = every SIMD occupied.
//  REGION B: read hB, fc MFMAs (matrix pipe) overlapped with the
//    corr-INDEPENDENT head of step t+1 (quat update, rotation, innovation,
//    LN partial sums - VALU pipe), write K.
//  REGION A: read K, corr_t, store out[t], then ASTEP: whh MFMAs first
//    (need only hB -> overlap the vp/pp/LN VALU tail), xB, wih MFMAs,
//    gate elementwise, write h.
// h_new D-fragment of wave w IS B-fragment tile kt=w (row formula 16w+4g+r
// == k formula): the GRU recurrence needs no transpose.  Scalar phase
// replicates across waves; pos/vel/q stay bitwise identical; wave 0 stores.
__global__
__attribute__((amdgpu_flat_work_group_size(256, 256), amdgpu_waves_per_eu(1, 1)))
void kalman_kernel(const float* __restrict__ inputs,
                   const float* __restrict__ ln_gamma,
                   const float* __restrict__ ln_beta,
                   const float* __restrict__ w_ih,
                   const float* __restrict__ w_hh,
                   const float* __restrict__ b_ih,
                   const float* __restrict__ b_hh,
                   const float* __restrict__ fc_w,
                   const float* __restrict__ fc_b,
                   float* __restrict__ out)
{
    __shared__ u32x2_t     s_h[4][64];    // h_new B-fragments, per kt tile
    __shared__ unsigned int s_Kp[24][16]; // K row-pairs (f16x2) x batch col  [V2-verbatim]

    const int tid  = threadIdx.x;
    const int lane = tid & 63;
    const int w    = tid >> 6;
    const int bq   = lane & 15;
    const int g    = lane >> 4;
    const int e    = blockIdx.x * 16 + bq;

    const int mtR = w, mtZ = 4 + w, mtN = 8 + w;

    // ---- pinned A-fragments (f16), this wave's M-slice ----
    f16x4 whhR[4], whhZ[4], whhN[4];
#pragma unroll
    for (int kt = 0; kt < 4; ++kt) {
        const float* rR = w_hh + (size_t)(16 * mtR + bq) * 64 + 16 * kt + 4 * g;
        const float* rZ = w_hh + (size_t)(16 * mtZ + bq) * 64 + 16 * kt + 4 * g;
        const float* rN = w_hh + (size_t)(16 * mtN + bq) * 64 + 16 * kt + 4 * g;
        whhR[kt] = mk4(rR[0], rR[1], rR[2], rR[3]);
        whhZ[kt] = mk4(rZ[0], rZ[1], rZ[2], rZ[3]);
        whhN[kt] = mk4(rN[0], rN[1], rN[2], rN[3]);
    }

    f16x4 wihR, wihZ, wihN;               // K=13 padded to 16 [V2-verbatim]
    {
        const float* rR = w_ih + (size_t)(16 * mtR + bq) * 13;
        const float* rZ = w_ih + (size_t)(16 * mtZ + bq) * 13;
        const float* rN = w_ih + (size_t)(16 * mtN + bq) * 13;
        const int k0 = 4 * g;
        const float m1 = (k0 + 1 < 13) ? 1.f : 0.f;
        const float m2 = (k0 + 2 < 13) ? 1.f : 0.f;
        const float m3 = (k0 + 3 < 13) ? 1.f : 0.f;
        wihR = mk4(rR[k0], m1 * rR[k0 + 1], m2 * rR[k0 + 2], m3 * rR[k0 + 3]);
        wihZ = mk4(rZ[k0], m1 * rZ[k0 + 1], m2 * rZ[k0 + 2], m3 * rZ[k0 + 3]);
        wihN = mk4(rN[k0], m1 * rN[k0 + 1], m2 * rN[k0 + 2], m3 * rN[k0 + 3]);
    }

    f16x4 fcA[4];                         // fc tile mt=w (rows >=36 masked)
    {
        const int o = 16 * w + bq;
        const float* rp = fc_w + (size_t)(o < 36 ? o : 0) * 64;
        const float msk = (o < 36) ? 1.f : 0.f;
#pragma unroll
        for (int kt = 0; kt < 4; ++kt) {
            const float* cp = rp + 16 * kt + 4 * g;
            fcA[kt] = mk4(msk * cp[0], msk * cp[1], msk * cp[2], msk * cp[3]);
        }
    }

    // ---- biases in D-layout (row = 16*mt + 4*g + r) ----
    f32x4 br, bz, bin, bhn, fcb4;
#pragma unroll
    for (int r = 0; r < 4; ++r) {
        const int oR = 16 * mtR + 4 * g + r;
        const int oZ = 16 * mtZ + 4 * g + r;
        const int oN = 16 * mtN + 4 * g + r;
        br[r]  = b_ih[oR] + b_hh[oR];
        bz[r]  = b_ih[oZ] + b_hh[oZ];
        bin[r] = b_ih[oN];
        bhn[r] = b_hh[oN];
        const int oF = 16 * w + 4 * g + r;
        fcb4[r] = (oF < 36) ? fc_b[oF] : 0.f;
    }

    float gamx[4], betx[4];
#pragma unroll
    for (int j = 0; j < 4; ++j) {
        const int k = 4 * g + j;
        gamx[j] = (k < 13) ? ln_gamma[k] : 0.f;
        betx[j] = (k < 13) ? ln_beta[k]  : 0.f;
    }

    // ---- state ----
    float q0 = 1.0f, q1 = 0.f, q2 = 0.f, q3 = 0.f;   // q entering next head
    float qpn0, qpn1, qpn2, qpn3;                    // q_pred from last head
    float aw0, aw1, aw2;                             // accel_world from last head
    float innc0, innc1, innc2, innc3, innc4, innc5;  // innovation for pending corr
    float innx0, innx1, innx2, innx3, innx4, innx5;  // innovation from last head
    float S1h, S2h;                                  // LN partial sums (10 ch)
    float vpx, vpy, vpz, ppx, ppy, ppz;              // predicted v/p (pre-corr)
    f32x4 hstate = f32x4{0.f, 0.f, 0.f, 0.f};
    f16x4 hB[4];
#pragma unroll
    for (int i = 0; i < 4; ++i) hB[i] = mk4(0.f, 0.f, 0.f, 0.f);

    const float* ip = inputs + (size_t)e * TT * 9;
    float*       op = out    + (size_t)e * TT * 10;

    float cur[9], nxt[9];
#pragma unroll
    for (int k = 0; k < 9; ++k) cur[k] = ip[k];

    // corr-independent head: q_pred, accel_world, innovation, LN partials
    auto HEAD = [&]() {
        const float ax = cur[0], ay = cur[1], az = cur[2];
        const float gx = cur[3], gy = cur[4], gz = cur[5];
        const float mx = cur[6], my = cur[7], mz = cur[8];
        const float hx = gx * 0.005f, hy = gy * 0.005f, hz = gz * 0.005f;
        const float dn = frsq(1.0f + hx * hx + hy * hy + hz * hz);
        const float dw = dn, dx = hx * dn, dy = hy * dn, dz = hz * dn;
        const float a0 = q0 * dw - q1 * dx - q2 * dy - q3 * dz;
        const float a1 = q0 * dx + q1 * dw + q2 * dz - q3 * dy;
        const float a2 = q0 * dy - q1 * dz + q2 * dw + q3 * dx;
        const float a3 = q0 * dz + q1 * dy - q2 * dx + q3 * dw;
        const float pn = frsq(a0 * a0 + a1 * a1 + a2 * a2 + a3 * a3);
        qpn0 = a0 * pn; qpn1 = a1 * pn; qpn2 = a2 * pn; qpn3 = a3 * pn;

        const float r00 = 1.0f - 2.0f * (q2 * q2 + q3 * q3);
        const float r01 = 2.0f * (q1 * q2 - q3 * q0);
        const float r02 = 2.0f * (q1 * q3 + q2 * q0);
        const float r10 = 2.0f * (q1 * q2 + q3 * q0);
        const float r11 = 1.0f - 2.0f * (q1 * q1 + q3 * q3);
        const float r12 = 2.0f * (q2 * q3 - q1 * q0);
        const float r20 = 2.0f * (q1 * q3 - q2 * q0);
        const float r21 = 2.0f * (q2 * q3 + q1 * q0);
        const float r22 = 1.0f - 2.0f * (q1 * q1 + q2 * q2);
        aw0 = r00 * ax + r01 * ay + r02 * az;
        aw1 = r10 * ax + r11 * ay + r12 * az;
        aw2 = r20 * ax + r21 * ay + r22 * az - 9.81f;

        const float s00 = 1.0f - 2.0f * (qpn2 * qpn2 + qpn3 * qpn3);
        const float s01 = 2.0f * (qpn1 * qpn2 - qpn3 * qpn0);
        const float s02 = 2.0f * (qpn1 * qpn3 + qpn2 * qpn0);
        const float s20 = 2.0f * (qpn1 * qpn3 - qpn2 * qpn0);
        const float s21 = 2.0f * (qpn2 * qpn3 + qpn1 * qpn0);
        const float s22 = 1.0f - 2.0f * (qpn1 * qpn1 + qpn2 * qpn2);
        innx0 = mx - (20.0f * s00 - 40.0f * s20);
        innx1 = my - (20.0f * s01 - 40.0f * s21);
        innx2 = mz - (20.0f * s02 - 40.0f * s22);
        innx3 = ax - 9.81f * s20;
        innx4 = ay - 9.81f * s21;
        innx5 = az - 9.81f * s22;

        S1h = ((innx0 + innx1) + (innx2 + innx3)) + ((innx4 + innx5) +
              (qpn0 + qpn1)) + (qpn2 + qpn3);
        float s2 = innx0 * innx0;
        s2 = fmaf(innx1, innx1, s2); s2 = fmaf(innx2, innx2, s2);
        s2 = fmaf(innx3, innx3, s2); s2 = fmaf(innx4, innx4, s2);
        s2 = fmaf(innx5, innx5, s2); s2 = fmaf(qpn0, qpn0, s2);
        s2 = fmaf(qpn1, qpn1, s2);   s2 = fmaf(qpn2, qpn2, s2);
        s2 = fmaf(qpn3, qpn3, s2);
        S2h = s2;
    };

    // gate step given corrected state (pn,vn); writes h, rotates state
    auto ASTEP = [&](float pn0, float pn1, float pn2,
                     float vn0, float vn1, float vn2) {
        // whh MFMAs first: depend only on hB -> overlap with VALU below
        f32x4 ar = br, az4 = bz, nhh = bhn;
#pragma unroll
        for (int kt = 0; kt < 4; ++kt) {
            ar  = mfma16(whhR[kt], hB[kt], ar);
            az4 = mfma16(whhZ[kt], hB[kt], az4);
            nhh = mfma16(whhN[kt], hB[kt], nhh);
        }

        vpx = fmaf(aw0, 0.01f, vn0);
        vpy = fmaf(aw1, 0.01f, vn1);
        vpz = fmaf(aw2, 0.01f, vn2);
        ppx = fmaf(vn0, 0.01f, fmaf(aw0, 5e-5f, pn0));
        ppy = fmaf(vn1, 0.01f, fmaf(aw1, 5e-5f, pn1));
        ppz = fmaf(vn2, 0.01f, fmaf(aw2, 5e-5f, pn2));

        const float mu = (S1h + ((vpx + vpy) + vpz)) * (1.0f / 13.0f);
        float s2 = S2h;
        s2 = fmaf(vpx, vpx, s2); s2 = fmaf(vpy, vpy, s2); s2 = fmaf(vpz, vpz, s2);
        const float var = fmaf(-mu, mu, s2 * (1.0f / 13.0f));
        const float sc = frsq(var + 1e-5f);

        // this lane's 4 LN channels (ch = 4g..4g+3 of [inn6, vp3, qp4])
        const float c0 = g == 0 ? innx0 : g == 1 ? innx4 : g == 2 ? vpz  : qpn3;
        const float c1 = g == 0 ? innx1 : g == 1 ? innx5 : g == 2 ? qpn0 : 0.f;
        const float c2 = g == 0 ? innx2 : g == 1 ? vpx   : g == 2 ? qpn1 : 0.f;
        const float c3 = g == 0 ? innx3 : g == 1 ? vpy   : g == 2 ? qpn2 : 0.f;
        const f16x4 xB = mk4((c0 - mu) * sc * gamx[0] + betx[0],
                             (c1 - mu) * sc * gamx[1] + betx[1],
                             (c2 - mu) * sc * gamx[2] + betx[2],
                             (c3 - mu) * sc * gamx[3] + betx[3]);

        ar  = mfma16(wihR, xB, ar);
        az4 = mfma16(wihZ, xB, az4);
        const f32x4 nin = mfma16(wihN, xB, bin);

        f32x4 hv = hstate;
#pragma unroll
        for (int r = 0; r < 4; ++r) {
            const float rr = sigm(ar[r]);
            const float zz = sigm(az4[r]);
            const float nn = tanh_fast(nin[r] + rr * nhh[r]);
            hv[r] = fmaf(zz, hv[r] - nn, nn);
        }
        hstate = hv;
        const f16x4 hOwn = mk4(hv[0], hv[1], hv[2], hv[3]);
        s_h[w][lane] = __builtin_bit_cast(u32x2_t, hOwn);

        // rotate state for next head / corr
        innc0 = innx0; innc1 = innx1; innc2 = innx2;
        innc3 = innx3; innc4 = innx4; innc5 = innx5;
        q0 = qpn0; q1 = qpn1; q2 = qpn2; q3 = qpn3;
    };

    // ---- prologue: step 0 (pos=vel=0, h_prev=0) ----
    HEAD();
    ASTEP(0.f, 0.f, 0.f, 0.f, 0.f, 0.f);
#pragma unroll
    for (int k = 0; k < 9; ++k) cur[k] = ip[9 + k];   // input t=1
    __syncthreads();

    for (int t = 0; t < TT; ++t) {
        // ================= REGION B =================
#pragma unroll
        for (int kt = 0; kt < 4; ++kt)
            hB[kt] = __builtin_bit_cast(f16x4, s_h[kt][lane]);

        {   // prefetch input t+2 (pattern hardware-verified in rounds 1/2)
            const int tf = (t + 2 < TT) ? (t + 2) : (TT - 1);
            const float* np = ip + (size_t)tf * 9;
            const f32x4u v0 = *(const f32x4u*)np;
            const f32x4u v1 = *(const f32x4u*)(np + 4);
            nxt[0] = v0[0]; nxt[1] = v0[1]; nxt[2] = v0[2]; nxt[3] = v0[3];
            nxt[4] = v1[0]; nxt[5] = v1[1]; nxt[6] = v1[2]; nxt[7] = v1[3];
            nxt[8] = np[8];
        }

        if (w < 3) {                       // fc on matrix pipe [V2-verbatim]
            f32x4 a = mfma16(fcA[0], hB[0], fcb4);
#pragma unroll
            for (int kt = 1; kt < 4; ++kt) a = mfma16(fcA[kt], hB[kt], a);
            s_Kp[8 * w + 2 * g][bq]     = __builtin_bit_cast(unsigned int, pk16(a[0], a[1]));
            s_Kp[8 * w + 2 * g + 1][bq] = __builtin_bit_cast(unsigned int, pk16(a[2], a[3]));
        }

        if (t < TT - 1) HEAD();            // head for t+1 on VALU pipe
        __syncthreads();

        // ================= REGION A =================
        h2_t K2[18];                       // [V2-verbatim broadcast reads]
#pragma unroll
        for (int rp = 0; rp < 18; ++rp)
            K2[rp] = __builtin_bit_cast(h2_t, s_Kp[rp][bq]);

        const h2_t in0 = pk16(innc0, innc1);
        const h2_t in1 = pk16(innc2, innc3);
        const h2_t in2 = pk16(innc4, innc5);
        float c[6];
#pragma unroll
        for (int i = 0; i < 6; ++i)
            c[i] = fdot2(K2[3 * i + 0], in0,
                   fdot2(K2[3 * i + 1], in1,
                   fdot2(K2[3 * i + 2], in2, 0.f)));

        const float pn0 = ppx + c[0], pn1 = ppy + c[1], pn2 = ppz + c[2];
        const float vn0 = vpx + c[3], vn1 = vpy + c[4], vn2 = vpz + c[5];

        if (w == 0) {                      // out[t] = [p_corr, v_corr, q_pred_t]
            float* o0 = op + (size_t)t * 10;
            if (g == 0) {
                *(f32x4u*)(o0) = f32x4u{pn0, pn1, pn2, vn0};
            } else if (g == 1) {
                *(f32x4u*)(o0 + 4) = f32x4u{vn1, vn2, q0, q1};
            } else if (g == 2) {
                o0[8] = q2; o0[9] = q3;
            }
        }

        if (t == TT - 1) break;

        ASTEP(pn0, pn1, pn2, vn0, vn1, vn2);
#pragma unroll
        for (int k = 0; k < 9; ++k) cur[k] = nxt[k];
        __syncthreads();
    }
}

extern "C" void kernel_launch(void* const* d_in, const int* in_sizes, int n_in,
                              void* d_out, int out_size, void* d_ws, size_t ws_size,
                              hipStream_t stream) {
    const float* inputs   = (const float*)d_in[0];
    const float* ln_gamma = (const float*)d_in[1];
    const float* ln_beta  = (const float*)d_in[2];
    const float* w_ih     = (const float*)d_in[3];
    const float* w_hh     = (const float*)d_in[4];
    const float* b_ih     = (const float*)d_in[5];
    const float* b_hh     = (const float*)d_in[6];
    const float* fc_w     = (const float*)d_in[7];
    const float* fc_b     = (const float*)d_in[8];
    float* out = (float*)d_out;

    const int B = in_sizes[0] / (TT * 9);
    kalman_kernel<<<dim3(B / 16), dim3(256), 0, stream>>>(
        inputs, ln_gamma, ln_beta, w_ih, w_hh, b_ih, b_hh, fc_w, fc_b, out);
}